// Round 1
// baseline (652.576 us; speedup 1.0000x reference)
//
#include <hip/hip_runtime.h>
#include <hip/hip_fp16.h>
#include <stdint.h>

typedef _Float16 f16;
typedef _Float16 f16x8 __attribute__((ext_vector_type(8)));
typedef _Float16 f16x4 __attribute__((ext_vector_type(4)));
typedef _Float16 f16x2 __attribute__((ext_vector_type(2)));
typedef float f32x4 __attribute__((ext_vector_type(4)));
typedef float f32x2 __attribute__((ext_vector_type(2)));

#define B_ 4
#define N_ 16384
#define M_ 4096
#define C1_ 128
#define C2_ 256
#define BNTOT 65536  // B_*N_

// ---------------- async global->LDS 16B ----------------
__device__ __forceinline__ void gload_lds16(const void* g, void* l) {
    __builtin_amdgcn_global_load_lds(
        (const __attribute__((address_space(1))) void*)g,
        (__attribute__((address_space(3))) void*)l, 16, 0, 0);
}

// ---------------- kernel: fp32 -> fp16 convert ----------------
__global__ void conv_f16_kernel(const float* __restrict__ s, f16* __restrict__ d, int n) {
    for (int i = blockIdx.x * blockDim.x + threadIdx.x; i < n; i += gridDim.x * blockDim.x)
        d[i] = (f16)s[i];
}

// ---------------- kernel: 3-NN search ----------------
// One thread per query point; xyz2 of this batch staged in LDS (SoA, 48KB).
// Direct squared-diff distance (no cancellation) -> ordering matches the true
// (fp64) ordering; strict < keeps lowest index on ties like lax.top_k.
__global__ __launch_bounds__(256) void nn_kernel(
    const float* __restrict__ xyz1, const float* __restrict__ xyz2,
    int* __restrict__ idx_out, float* __restrict__ w_out) {
    __shared__ __align__(16) float xs[M_];
    __shared__ __align__(16) float ys[M_];
    __shared__ __align__(16) float zs[M_];
    int b = blockIdx.x >> 6;             // 64 blocks per batch (N/256)
    int n0 = (blockIdx.x & 63) << 8;
    const float* x2 = xyz2 + (size_t)b * M_ * 3;
    for (int m = threadIdx.x; m < M_; m += 256) {
        xs[m] = x2[m * 3 + 0];
        ys[m] = x2[m * 3 + 1];
        zs[m] = x2[m * 3 + 2];
    }
    __syncthreads();
    int n = n0 + threadIdx.x;
    const float* q = xyz1 + ((size_t)b * N_ + n) * 3;
    float qx = q[0], qy = q[1], qz = q[2];
    float k0 = 3.4e38f, k1 = 3.4e38f, k2 = 3.4e38f;
    int i0 = 0, i1 = 0, i2 = 0;
    for (int m = 0; m < M_; m += 4) {
        f32x4 xv = *(const f32x4*)&xs[m];   // uniform addr -> LDS broadcast
        f32x4 yv = *(const f32x4*)&ys[m];
        f32x4 zv = *(const f32x4*)&zs[m];
#pragma unroll
        for (int u = 0; u < 4; ++u) {
            float dx = qx - xv[u], dy = qy - yv[u], dz = qz - zv[u];
            float d2 = fmaf(dx, dx, fmaf(dy, dy, dz * dz));
            int mi = m + u;
            if (d2 < k2) {                   // rare after warmup
                if (d2 < k1) {
                    k2 = k1; i2 = i1;
                    if (d2 < k0) { k1 = k0; i1 = i0; k0 = d2; i0 = mi; }
                    else         { k1 = d2; i1 = mi; }
                } else { k2 = d2; i2 = mi; }
            }
        }
    }
    float w0 = 1.0f / (k0 + 1e-8f);
    float w1 = 1.0f / (k1 + 1e-8f);
    float w2 = 1.0f / (k2 + 1e-8f);
    float ws = w0 + w1 + w2;
    w0 /= ws; w1 /= ws; w2 /= ws;
    size_t p = (size_t)b * N_ + n;
    idx_out[p * 3 + 0] = i0; idx_out[p * 3 + 1] = i1; idx_out[p * 3 + 2] = i2;
    w_out[p * 3 + 0] = w0;  w_out[p * 3 + 1] = w1;  w_out[p * 3 + 2] = w2;
}

// ---------------- kernel: gather-interp + concat -> x0 (fp16) ----------------
// One wave per point: lane handles 4 of 256 interp channels + 2 of 128 pts1 ch.
__global__ __launch_bounds__(256) void interp_kernel(
    const float* __restrict__ pts1, const float* __restrict__ pts2,
    const int* __restrict__ idxb, const float* __restrict__ wb,
    f16* __restrict__ x0) {
    int wave = threadIdx.x >> 6, lane = threadIdx.x & 63;
    size_t p = (size_t)blockIdx.x * 4 + wave;
    int b = (int)(p >> 14);  // N_=16384
    int j0 = idxb[p * 3 + 0], j1 = idxb[p * 3 + 1], j2 = idxb[p * 3 + 2];
    float w0 = wb[p * 3 + 0], w1 = wb[p * 3 + 1], w2 = wb[p * 3 + 2];
    const float* base2 = pts2 + (size_t)b * M_ * C2_;
    f32x4 a = *(const f32x4*)(base2 + (size_t)j0 * C2_ + lane * 4);
    f32x4 bv = *(const f32x4*)(base2 + (size_t)j1 * C2_ + lane * 4);
    f32x4 c = *(const f32x4*)(base2 + (size_t)j2 * C2_ + lane * 4);
    f16* xrow = x0 + p * (C1_ + C2_);
    f16x4 o;
#pragma unroll
    for (int j = 0; j < 4; ++j)
        o[j] = (f16)(w0 * a[j] + w1 * bv[j] + w2 * c[j]);
    *(f16x4*)(xrow + C1_ + lane * 4) = o;
    f32x2 p1 = *(const f32x2*)(pts1 + p * C1_ + lane * 2);
    f16x2 o2; o2[0] = (f16)p1[0]; o2[1] = (f16)p1[1];
    *(f16x2*)(xrow + lane * 2) = o2;
}

// ---------------- kernel: fp16 GEMM, H[m][o] = sum_c A[m][c] * W[o][c] ----------------
// 128x128 tile, BK=64, 4 waves (2x2), global_load_lds staging (m97 structure).
template <int K>
__global__ __launch_bounds__(256) void gemm_f16(
    const f16* __restrict__ A, const f16* __restrict__ W,
    f16* __restrict__ H, int Nn) {
    __shared__ __align__(16) f16 As[128 * 64];
    __shared__ __align__(16) f16 Bs[128 * 64];
    int tid = threadIdx.x;
    int lane = tid & 63, wave = tid >> 6;
    int wr = wave >> 1, wc = wave & 1;
    int bm0 = blockIdx.x * 128, bn0 = blockIdx.y * 128;
    const f16* Ab = A + (size_t)bm0 * K;
    const f16* Wb = W + (size_t)bn0 * K;
    int r = tid >> 3;            // 0..31
    int cc = (tid & 7) * 8;      // 0..56, 8 f16 = 16B
    f32x4 acc[4][4] = {};
    for (int kt = 0; kt < K; kt += 64) {
        __syncthreads();
#pragma unroll
        for (int i = 0; i < 4; ++i) {
            gload_lds16(Ab + (size_t)(i * 32 + r) * K + kt + cc, &As[(i * 32 + r) * 64 + cc]);
            gload_lds16(Wb + (size_t)(i * 32 + r) * K + kt + cc, &Bs[(i * 32 + r) * 64 + cc]);
        }
        __syncthreads();
#pragma unroll
        for (int kk = 0; kk < 2; ++kk) {
            f16x8 af[4], bf[4];
            int koff = kk * 32 + (lane >> 4) * 8;
#pragma unroll
            for (int mt = 0; mt < 4; ++mt)
                af[mt] = *(const f16x8*)&As[(wr * 64 + mt * 16 + (lane & 15)) * 64 + koff];
#pragma unroll
            for (int nt = 0; nt < 4; ++nt)
                bf[nt] = *(const f16x8*)&Bs[(wc * 64 + nt * 16 + (lane & 15)) * 64 + koff];
#pragma unroll
            for (int mt = 0; mt < 4; ++mt)
#pragma unroll
                for (int nt = 0; nt < 4; ++nt)
                    acc[mt][nt] = __builtin_amdgcn_mfma_f32_16x16x32_f16(af[mt], bf[nt], acc[mt][nt], 0, 0, 0);
        }
    }
    // epilogue: C/D layout col=lane&15, row=(lane>>4)*4+reg
    int rr = (lane >> 4) * 4;
    int cl = lane & 15;
#pragma unroll
    for (int mt = 0; mt < 4; ++mt) {
#pragma unroll
        for (int nt = 0; nt < 4; ++nt) {
            int row = bm0 + wr * 64 + mt * 16 + rr;
            int col = bn0 + wc * 64 + nt * 16 + cl;
#pragma unroll
            for (int j = 0; j < 4; ++j)
                H[(size_t)(row + j) * Nn + col] = (f16)acc[mt][nt][j];
        }
    }
}

// ---------------- kernel: per-channel sum/sumsq (atomics) ----------------
__global__ __launch_bounds__(256) void stats_kernel(
    const f16* __restrict__ H, float* __restrict__ sums, float* __restrict__ sumsq, int Nn) {
    int tid = threadIdx.x;
    int c = tid & (Nn - 1);
    int rsub = tid / Nn;
    int rstep = 256 / Nn;
    int r0 = blockIdx.x * 256;
    float s = 0.f, s2 = 0.f;
    for (int rr = r0 + rsub; rr < r0 + 256; rr += rstep) {
        float v = (float)H[(size_t)rr * Nn + c];
        s += v;
        s2 = fmaf(v, v, s2);
    }
    atomicAdd(&sums[c], s);
    atomicAdd(&sumsq[c], s2);
}

// ---------------- kernel: finalize BN -> scale/shift ----------------
__global__ void finalize_kernel(const float* __restrict__ sums, const float* __restrict__ sumsq,
                                const float* __restrict__ g, const float* __restrict__ be,
                                float* __restrict__ scale, float* __restrict__ shift, int Nn) {
    int c = threadIdx.x;
    if (c < Nn) {
        const float invM = 1.0f / 65536.0f;
        float mean = sums[c] * invM;
        float var = sumsq[c] * invM - mean * mean;
        float rstd = rsqrtf(var + 1e-5f);
        float sc = rstd * g[c];
        scale[c] = sc;
        shift[c] = be[c] - mean * sc;
    }
}

// ---------------- kernel: BN-apply + ReLU (in-place f16 or fp32 out) ----------------
template <bool OUT16>
__global__ __launch_bounds__(256) void bnrelu_kernel(
    const f16* __restrict__ H, const float* __restrict__ scale, const float* __restrict__ shift,
    f16* __restrict__ o16, float* __restrict__ o32, int Nn) {
    size_t t = (size_t)blockIdx.x * 256 + threadIdx.x;
    size_t base = t * 8;
    int c0 = (int)(base & (size_t)(Nn - 1));
    f16x8 v = *(const f16x8*)(H + base);
    float r[8];
#pragma unroll
    for (int j = 0; j < 8; ++j)
        r[j] = fmaxf(0.0f, fmaf((float)v[j], scale[c0 + j], shift[c0 + j]));
    if (OUT16) {
        f16x8 ov;
#pragma unroll
        for (int j = 0; j < 8; ++j) ov[j] = (f16)r[j];
        *(f16x8*)(o16 + base) = ov;
    } else {
        f32x4 a = {r[0], r[1], r[2], r[3]};
        f32x4 b = {r[4], r[5], r[6], r[7]};
        *(f32x4*)(o32 + base) = a;
        *(f32x4*)(o32 + base + 4) = b;
    }
}

extern "C" void kernel_launch(void* const* d_in, const int* in_sizes, int n_in,
                              void* d_out, int out_size, void* d_ws, size_t ws_size,
                              hipStream_t stream) {
    const float* xyz1 = (const float*)d_in[0];
    const float* xyz2 = (const float*)d_in[1];
    const float* pts1 = (const float*)d_in[2];
    const float* pts2 = (const float*)d_in[3];
    const float* w0f = (const float*)d_in[4];
    const float* g0 = (const float*)d_in[6];
    const float* be0 = (const float*)d_in[7];
    const float* w1f = (const float*)d_in[8];
    const float* g1 = (const float*)d_in[10];
    const float* be1 = (const float*)d_in[11];
    const float* w2f = (const float*)d_in[12];
    const float* g2 = (const float*)d_in[14];
    const float* be2 = (const float*)d_in[15];
    // biases b{li} cancel exactly under training-mode BN -> unused.

    char* ws = (char*)d_ws;
    // layout (bytes):
    //   x0  : [0, 50331648)              65536x384 f16; reused as bufB after layer0
    //   bufA: [50331648, +33554432)      65536x256 f16
    //   wb  : [83886080, +393216)        all three weight matrices, f16
    //   idx : [84279296, +786432)        65536x3 i32
    //   wgt : [85065728, +786432)        65536x3 f32
    //   stat: [85852160, +4096)          sums/sumsq/scale/shift x256 f32
    f16* x0 = (f16*)(ws + 0);
    f16* bufA = (f16*)(ws + 50331648);
    f16* bufB = x0;  // alias: x0 dead after layer-0 GEMM
    f16* wb0 = (f16*)(ws + 83886080);
    f16* wb1 = wb0 + 98304;
    f16* wb2 = wb1 + 65536;
    int* idxb = (int*)(ws + 84279296);
    float* wgt = (float*)(ws + 85065728);
    float* stats = (float*)(ws + 85852160);
    float* sums = stats, *sumsq = stats + 256, *scale = stats + 512, *shift = stats + 768;

    // weights -> fp16
    conv_f16_kernel<<<128, 256, 0, stream>>>(w0f, wb0, 98304);
    conv_f16_kernel<<<128, 256, 0, stream>>>(w1f, wb1, 65536);
    conv_f16_kernel<<<128, 256, 0, stream>>>(w2f, wb2, 32768);

    // 3-NN + interpolation + concat
    nn_kernel<<<256, 256, 0, stream>>>(xyz1, xyz2, idxb, wgt);
    interp_kernel<<<BNTOT / 4, 256, 0, stream>>>(pts1, pts2, idxb, wgt, x0);

    // ---- layer 0: 384 -> 256 ----
    gemm_f16<384><<<dim3(512, 2), 256, 0, stream>>>(x0, wb0, bufA, 256);
    hipMemsetAsync(sums, 0, 2048, stream);
    stats_kernel<<<256, 256, 0, stream>>>(bufA, sums, sumsq, 256);
    finalize_kernel<<<1, 256, 0, stream>>>(sums, sumsq, g0, be0, scale, shift, 256);
    bnrelu_kernel<true><<<8192, 256, 0, stream>>>(bufA, scale, shift, bufA, nullptr, 256);

    // ---- layer 1: 256 -> 256 ----
    gemm_f16<256><<<dim3(512, 2), 256, 0, stream>>>(bufA, wb1, bufB, 256);
    hipMemsetAsync(sums, 0, 2048, stream);
    stats_kernel<<<256, 256, 0, stream>>>(bufB, sums, sumsq, 256);
    finalize_kernel<<<1, 256, 0, stream>>>(sums, sumsq, g1, be1, scale, shift, 256);
    bnrelu_kernel<true><<<8192, 256, 0, stream>>>(bufB, scale, shift, bufB, nullptr, 256);

    // ---- layer 2: 256 -> 128 ----
    gemm_f16<256><<<dim3(512, 1), 256, 0, stream>>>(bufB, wb2, bufA, 128);
    hipMemsetAsync(sums, 0, 2048, stream);
    stats_kernel<<<256, 256, 0, stream>>>(bufA, sums, sumsq, 128);
    finalize_kernel<<<1, 256, 0, stream>>>(sums, sumsq, g2, be2, scale, shift, 128);
    bnrelu_kernel<false><<<4096, 256, 0, stream>>>(bufA, scale, shift, nullptr, (float*)d_out, 128);
}

// Round 2
// 510.273 us; speedup vs baseline: 1.2789x; 1.2789x over previous
//
#include <hip/hip_runtime.h>
#include <hip/hip_fp16.h>
#include <stdint.h>

typedef _Float16 f16;
typedef _Float16 f16x8 __attribute__((ext_vector_type(8)));
typedef _Float16 f16x4 __attribute__((ext_vector_type(4)));
typedef _Float16 f16x2 __attribute__((ext_vector_type(2)));
typedef float f32x4 __attribute__((ext_vector_type(4)));
typedef float f32x2 __attribute__((ext_vector_type(2)));

#define B_ 4
#define N_ 16384
#define M_ 4096
#define C1_ 128
#define C2_ 256
#define BNTOT 65536  // B_*N_

#define SPLIT 8
#define CHUNK (M_ / SPLIT)  // 512

// ---------------- async global->LDS 16B ----------------
__device__ __forceinline__ void gload_lds16(const void* g, void* l) {
    __builtin_amdgcn_global_load_lds(
        (const __attribute__((address_space(1))) void*)g,
        (__attribute__((address_space(3))) void*)l, 16, 0, 0);
}

// ---------------- kernel: fp32 -> fp16 convert ----------------
__global__ void conv_f16_kernel(const float* __restrict__ s, f16* __restrict__ d, int n) {
    for (int i = blockIdx.x * blockDim.x + threadIdx.x; i < n; i += gridDim.x * blockDim.x)
        d[i] = (f16)s[i];
}

// ---------------- kernel: 3-NN partial search over one M-chunk ----------------
// grid = (BNTOT/256) * SPLIT blocks. Each block: 256 query points x one
// 512-candidate chunk of xyz2 (staged SoA in 6KB LDS -> 8 blocks/CU).
// Direct squared-diff distance (no cancellation); strict < insertion keeps
// lowest index on ties like lax.top_k.
__global__ __launch_bounds__(256) void nn_part_kernel(
    const float* __restrict__ xyz1, const float* __restrict__ xyz2,
    float* __restrict__ cd, int* __restrict__ ci) {
    __shared__ __align__(16) float xs[CHUNK];
    __shared__ __align__(16) float ys[CHUNK];
    __shared__ __align__(16) float zs[CHUNK];
    int bid = blockIdx.x;
    int part = bid & (SPLIT - 1);
    int pblk = bid >> 3;                 // 0..255 point-block
    int b = pblk >> 6;                   // 64 point-blocks per batch
    int m0 = part * CHUNK;
    const float* x2 = xyz2 + ((size_t)b * M_ + m0) * 3;
    for (int m = threadIdx.x; m < CHUNK; m += 256) {
        xs[m] = x2[m * 3 + 0];
        ys[m] = x2[m * 3 + 1];
        zs[m] = x2[m * 3 + 2];
    }
    __syncthreads();
    size_t p = (size_t)pblk * 256 + threadIdx.x;
    const float* q = xyz1 + p * 3;
    float qx = q[0], qy = q[1], qz = q[2];
    float k0 = 3.4e38f, k1 = 3.4e38f, k2 = 3.4e38f;
    int i0 = 0, i1 = 0, i2 = 0;
    for (int m = 0; m < CHUNK; m += 4) {
        f32x4 xv = *(const f32x4*)&xs[m];   // uniform addr -> LDS broadcast
        f32x4 yv = *(const f32x4*)&ys[m];
        f32x4 zv = *(const f32x4*)&zs[m];
#pragma unroll
        for (int u = 0; u < 4; ++u) {
            float dx = qx - xv[u], dy = qy - yv[u], dz = qz - zv[u];
            float d2 = fmaf(dx, dx, fmaf(dy, dy, dz * dz));
            int mi = m0 + m + u;
            if (d2 < k2) {                   // rare after warmup
                if (d2 < k1) {
                    k2 = k1; i2 = i1;
                    if (d2 < k0) { k1 = k0; i1 = i0; k0 = d2; i0 = mi; }
                    else         { k1 = d2; i1 = mi; }
                } else { k2 = d2; i2 = mi; }
            }
        }
    }
    float* cdp = cd + (p * SPLIT + part) * 3;
    int* cip = ci + (p * SPLIT + part) * 3;
    cdp[0] = k0; cdp[1] = k1; cdp[2] = k2;
    cip[0] = i0; cip[1] = i1; cip[2] = i2;
}

// ---------------- kernel: merge SPLIT x 3 candidates -> top-3 + weights ----------------
// Chunks visited in ascending index order, strict < insertion -> identical
// tie-break to a single sequential scan (= lax.top_k lowest-index-first).
__global__ __launch_bounds__(256) void nn_merge_kernel(
    const float* __restrict__ cd, const int* __restrict__ ci,
    int* __restrict__ idx_out, float* __restrict__ w_out) {
    size_t p = (size_t)blockIdx.x * 256 + threadIdx.x;
    const float* cdp = cd + p * (SPLIT * 3);
    const int* cip = ci + p * (SPLIT * 3);
    float k0 = 3.4e38f, k1 = 3.4e38f, k2 = 3.4e38f;
    int i0 = 0, i1 = 0, i2 = 0;
#pragma unroll
    for (int t = 0; t < SPLIT * 3; ++t) {
        float d2 = cdp[t];
        int mi = cip[t];
        if (d2 < k2) {
            if (d2 < k1) {
                k2 = k1; i2 = i1;
                if (d2 < k0) { k1 = k0; i1 = i0; k0 = d2; i0 = mi; }
                else         { k1 = d2; i1 = mi; }
            } else { k2 = d2; i2 = mi; }
        }
    }
    float w0 = 1.0f / (k0 + 1e-8f);
    float w1 = 1.0f / (k1 + 1e-8f);
    float w2 = 1.0f / (k2 + 1e-8f);
    float ws = w0 + w1 + w2;
    w0 /= ws; w1 /= ws; w2 /= ws;
    idx_out[p * 3 + 0] = i0; idx_out[p * 3 + 1] = i1; idx_out[p * 3 + 2] = i2;
    w_out[p * 3 + 0] = w0;  w_out[p * 3 + 1] = w1;  w_out[p * 3 + 2] = w2;
}

// ---------------- kernel: gather-interp + concat -> x0 (fp16) ----------------
// One wave per point: lane handles 4 of 256 interp channels + 2 of 128 pts1 ch.
__global__ __launch_bounds__(256) void interp_kernel(
    const float* __restrict__ pts1, const float* __restrict__ pts2,
    const int* __restrict__ idxb, const float* __restrict__ wb,
    f16* __restrict__ x0) {
    int wave = threadIdx.x >> 6, lane = threadIdx.x & 63;
    size_t p = (size_t)blockIdx.x * 4 + wave;
    int b = (int)(p >> 14);  // N_=16384
    int j0 = idxb[p * 3 + 0], j1 = idxb[p * 3 + 1], j2 = idxb[p * 3 + 2];
    float w0 = wb[p * 3 + 0], w1 = wb[p * 3 + 1], w2 = wb[p * 3 + 2];
    const float* base2 = pts2 + (size_t)b * M_ * C2_;
    f32x4 a = *(const f32x4*)(base2 + (size_t)j0 * C2_ + lane * 4);
    f32x4 bv = *(const f32x4*)(base2 + (size_t)j1 * C2_ + lane * 4);
    f32x4 c = *(const f32x4*)(base2 + (size_t)j2 * C2_ + lane * 4);
    f16* xrow = x0 + p * (C1_ + C2_);
    f16x4 o;
#pragma unroll
    for (int j = 0; j < 4; ++j)
        o[j] = (f16)(w0 * a[j] + w1 * bv[j] + w2 * c[j]);
    *(f16x4*)(xrow + C1_ + lane * 4) = o;
    f32x2 p1 = *(const f32x2*)(pts1 + p * C1_ + lane * 2);
    f16x2 o2; o2[0] = (f16)p1[0]; o2[1] = (f16)p1[1];
    *(f16x2*)(xrow + lane * 2) = o2;
}

// ---------------- kernel: fp16 GEMM, H[m][o] = sum_c A[m][c] * W[o][c] ----------------
// 128x128 tile, BK=64, 4 waves (2x2), global_load_lds staging (m97 structure).
template <int K>
__global__ __launch_bounds__(256) void gemm_f16(
    const f16* __restrict__ A, const f16* __restrict__ W,
    f16* __restrict__ H, int Nn) {
    __shared__ __align__(16) f16 As[128 * 64];
    __shared__ __align__(16) f16 Bs[128 * 64];
    int tid = threadIdx.x;
    int lane = tid & 63, wave = tid >> 6;
    int wr = wave >> 1, wc = wave & 1;
    int bm0 = blockIdx.x * 128, bn0 = blockIdx.y * 128;
    const f16* Ab = A + (size_t)bm0 * K;
    const f16* Wb = W + (size_t)bn0 * K;
    int r = tid >> 3;            // 0..31
    int cc = (tid & 7) * 8;      // 0..56, 8 f16 = 16B
    f32x4 acc[4][4] = {};
    for (int kt = 0; kt < K; kt += 64) {
        __syncthreads();
#pragma unroll
        for (int i = 0; i < 4; ++i) {
            gload_lds16(Ab + (size_t)(i * 32 + r) * K + kt + cc, &As[(i * 32 + r) * 64 + cc]);
            gload_lds16(Wb + (size_t)(i * 32 + r) * K + kt + cc, &Bs[(i * 32 + r) * 64 + cc]);
        }
        __syncthreads();
#pragma unroll
        for (int kk = 0; kk < 2; ++kk) {
            f16x8 af[4], bf[4];
            int koff = kk * 32 + (lane >> 4) * 8;
#pragma unroll
            for (int mt = 0; mt < 4; ++mt)
                af[mt] = *(const f16x8*)&As[(wr * 64 + mt * 16 + (lane & 15)) * 64 + koff];
#pragma unroll
            for (int nt = 0; nt < 4; ++nt)
                bf[nt] = *(const f16x8*)&Bs[(wc * 64 + nt * 16 + (lane & 15)) * 64 + koff];
#pragma unroll
            for (int mt = 0; mt < 4; ++mt)
#pragma unroll
                for (int nt = 0; nt < 4; ++nt)
                    acc[mt][nt] = __builtin_amdgcn_mfma_f32_16x16x32_f16(af[mt], bf[nt], acc[mt][nt], 0, 0, 0);
        }
    }
    // epilogue: C/D layout col=lane&15, row=(lane>>4)*4+reg
    int rr = (lane >> 4) * 4;
    int cl = lane & 15;
#pragma unroll
    for (int mt = 0; mt < 4; ++mt) {
#pragma unroll
        for (int nt = 0; nt < 4; ++nt) {
            int row = bm0 + wr * 64 + mt * 16 + rr;
            int col = bn0 + wc * 64 + nt * 16 + cl;
#pragma unroll
            for (int j = 0; j < 4; ++j)
                H[(size_t)(row + j) * Nn + col] = (f16)acc[mt][nt][j];
        }
    }
}

// ---------------- kernel: per-channel sum/sumsq (atomics) ----------------
__global__ __launch_bounds__(256) void stats_kernel(
    const f16* __restrict__ H, float* __restrict__ sums, float* __restrict__ sumsq, int Nn) {
    int tid = threadIdx.x;
    int c = tid & (Nn - 1);
    int rsub = tid / Nn;
    int rstep = 256 / Nn;
    int r0 = blockIdx.x * 256;
    float s = 0.f, s2 = 0.f;
    for (int rr = r0 + rsub; rr < r0 + 256; rr += rstep) {
        float v = (float)H[(size_t)rr * Nn + c];
        s += v;
        s2 = fmaf(v, v, s2);
    }
    atomicAdd(&sums[c], s);
    atomicAdd(&sumsq[c], s2);
}

// ---------------- kernel: finalize BN -> scale/shift ----------------
__global__ void finalize_kernel(const float* __restrict__ sums, const float* __restrict__ sumsq,
                                const float* __restrict__ g, const float* __restrict__ be,
                                float* __restrict__ scale, float* __restrict__ shift, int Nn) {
    int c = threadIdx.x;
    if (c < Nn) {
        const float invM = 1.0f / 65536.0f;
        float mean = sums[c] * invM;
        float var = sumsq[c] * invM - mean * mean;
        float rstd = rsqrtf(var + 1e-5f);
        float sc = rstd * g[c];
        scale[c] = sc;
        shift[c] = be[c] - mean * sc;
    }
}

// ---------------- kernel: BN-apply + ReLU (in-place f16 or fp32 out) ----------------
template <bool OUT16>
__global__ __launch_bounds__(256) void bnrelu_kernel(
    const f16* __restrict__ H, const float* __restrict__ scale, const float* __restrict__ shift,
    f16* __restrict__ o16, float* __restrict__ o32, int Nn) {
    size_t t = (size_t)blockIdx.x * 256 + threadIdx.x;
    size_t base = t * 8;
    int c0 = (int)(base & (size_t)(Nn - 1));
    f16x8 v = *(const f16x8*)(H + base);
    float r[8];
#pragma unroll
    for (int j = 0; j < 8; ++j)
        r[j] = fmaxf(0.0f, fmaf((float)v[j], scale[c0 + j], shift[c0 + j]));
    if (OUT16) {
        f16x8 ov;
#pragma unroll
        for (int j = 0; j < 8; ++j) ov[j] = (f16)r[j];
        *(f16x8*)(o16 + base) = ov;
    } else {
        f32x4 a = {r[0], r[1], r[2], r[3]};
        f32x4 b = {r[4], r[5], r[6], r[7]};
        *(f32x4*)(o32 + base) = a;
        *(f32x4*)(o32 + base + 4) = b;
    }
}

extern "C" void kernel_launch(void* const* d_in, const int* in_sizes, int n_in,
                              void* d_out, int out_size, void* d_ws, size_t ws_size,
                              hipStream_t stream) {
    const float* xyz1 = (const float*)d_in[0];
    const float* xyz2 = (const float*)d_in[1];
    const float* pts1 = (const float*)d_in[2];
    const float* pts2 = (const float*)d_in[3];
    const float* w0f = (const float*)d_in[4];
    const float* g0 = (const float*)d_in[6];
    const float* be0 = (const float*)d_in[7];
    const float* w1f = (const float*)d_in[8];
    const float* g1 = (const float*)d_in[10];
    const float* be1 = (const float*)d_in[11];
    const float* w2f = (const float*)d_in[12];
    const float* g2 = (const float*)d_in[14];
    const float* be2 = (const float*)d_in[15];
    // biases b{li} cancel exactly under training-mode BN -> unused.

    char* ws = (char*)d_ws;
    // layout (bytes):
    //   x0  : [0, 50331648)              65536x384 f16; reused as bufB after layer0
    //   bufA: [50331648, +33554432)      65536x256 f16
    //         (candidate buffers cd/ci alias bufA: dead before layer-0 GEMM)
    //   wb  : [83886080, +393216)        all three weight matrices, f16
    //   idx : [84279296, +786432)        65536x3 i32
    //   wgt : [85065728, +786432)        65536x3 f32
    //   stat: [85852160, +4096)          sums/sumsq/scale/shift x256 f32
    f16* x0 = (f16*)(ws + 0);
    f16* bufA = (f16*)(ws + 50331648);
    f16* bufB = x0;  // alias: x0 dead after layer-0 GEMM
    float* cand_d = (float*)(ws + 50331648);               // 65536*8*3 f32 = 6.29MB
    int* cand_i = (int*)(ws + 50331648 + 6291456);         // 65536*8*3 i32 = 6.29MB
    f16* wb0 = (f16*)(ws + 83886080);
    f16* wb1 = wb0 + 98304;
    f16* wb2 = wb1 + 65536;
    int* idxb = (int*)(ws + 84279296);
    float* wgt = (float*)(ws + 85065728);
    float* stats = (float*)(ws + 85852160);
    float* sums = stats, *sumsq = stats + 256, *scale = stats + 512, *shift = stats + 768;

    // weights -> fp16
    conv_f16_kernel<<<128, 256, 0, stream>>>(w0f, wb0, 98304);
    conv_f16_kernel<<<128, 256, 0, stream>>>(w1f, wb1, 65536);
    conv_f16_kernel<<<128, 256, 0, stream>>>(w2f, wb2, 32768);

    // 3-NN (split-M partial scan + merge) + interpolation + concat
    nn_part_kernel<<<(BNTOT / 256) * SPLIT, 256, 0, stream>>>(xyz1, xyz2, cand_d, cand_i);
    nn_merge_kernel<<<BNTOT / 256, 256, 0, stream>>>(cand_d, cand_i, idxb, wgt);
    interp_kernel<<<BNTOT / 4, 256, 0, stream>>>(pts1, pts2, idxb, wgt, x0);

    // ---- layer 0: 384 -> 256 ----
    gemm_f16<384><<<dim3(512, 2), 256, 0, stream>>>(x0, wb0, bufA, 256);
    hipMemsetAsync(sums, 0, 2048, stream);
    stats_kernel<<<256, 256, 0, stream>>>(bufA, sums, sumsq, 256);
    finalize_kernel<<<1, 256, 0, stream>>>(sums, sumsq, g0, be0, scale, shift, 256);
    bnrelu_kernel<true><<<8192, 256, 0, stream>>>(bufA, scale, shift, bufA, nullptr, 256);

    // ---- layer 1: 256 -> 256 ----
    gemm_f16<256><<<dim3(512, 2), 256, 0, stream>>>(bufA, wb1, bufB, 256);
    hipMemsetAsync(sums, 0, 2048, stream);
    stats_kernel<<<256, 256, 0, stream>>>(bufB, sums, sumsq, 256);
    finalize_kernel<<<1, 256, 0, stream>>>(sums, sumsq, g1, be1, scale, shift, 256);
    bnrelu_kernel<true><<<8192, 256, 0, stream>>>(bufB, scale, shift, bufB, nullptr, 256);

    // ---- layer 2: 256 -> 128 ----
    gemm_f16<256><<<dim3(512, 1), 256, 0, stream>>>(bufB, wb2, bufA, 128);
    hipMemsetAsync(sums, 0, 2048, stream);
    stats_kernel<<<256, 256, 0, stream>>>(bufA, sums, sumsq, 128);
    finalize_kernel<<<1, 256, 0, stream>>>(sums, sumsq, g2, be2, scale, shift, 128);
    bnrelu_kernel<false><<<4096, 256, 0, stream>>>(bufA, scale, shift, nullptr, (float*)d_out, 128);
}